// Round 14
// baseline (539.762 us; speedup 1.0000x reference)
//
#include <hip/hip_runtime.h>
#include <hip/hip_bf16.h>

typedef __bf16 bf16x8 __attribute__((ext_vector_type(8)));
typedef __bf16 bf16x4 __attribute__((ext_vector_type(4)));
typedef float  f32x4  __attribute__((ext_vector_type(4)));
typedef float  f32x16 __attribute__((ext_vector_type(16)));
typedef float  f32x4a __attribute__((ext_vector_type(4))) __attribute__((aligned(4)));
typedef float  f32x2a __attribute__((ext_vector_type(2))) __attribute__((aligned(4)));

#define NPOS 49
#define NHEADS 8
#define SCALE_F 0.17677669529663687f

// ---- LDS: 4 per-wave slices of 13056 B = 52224 B total ----
// phase 0: smem[0..33792) = xwT [64 pos][264 ch] bf16 (overlays slices 0..2)
// phase A: slice+0 = vs [64 dd][68 pos] bf16 (8704 B)
// phase B: slice+0 = qk [49 pos][132 dd] bf16 (264 B rows; q=elem 0..63, k=64..127)
// phase C: Pb0 = slice+0, Pb1 = slice+6400 ([49 i][128 B] swizzled bf16 each)
// MODE 0 epilogue: smem[0..33792) = aoT [64][264] bf16
// NOTE: 2 blocks/CU is the register-determined equilibrium (Bf=128 VGPR +
// 64 acc, unified file ~192/wave); forcing 3 waves/SIMD spills ~90 regs and
// regresses 2x (measured r10/r12). Structure is interlocked: Bf-from-LDS
// needs xwT alive -> LDS>=77KB -> still 2 blocks/CU. Do NOT push occupancy.
#define SLICE_B   13056
#define QK_ROW_B  264
#define VS_ROW_B  136
#define P1_OFF    6400
#define XWT_PITCH 264
#define AOT_PITCH 264
#define LDS_BYTES 52224

static __device__ __forceinline__ f32x16 zero16() {
  f32x16 z;
#pragma unroll
  for (int i = 0; i < 16; ++i) z[i] = 0.f;
  return z;
}

// prep: bf16 weight copies + MFMA-fragment-packed copies + bias table
__global__ void prep_kernel(const float* __restrict__ Wq, const float* __restrict__ Wkv,
                            const float* __restrict__ Wo, const float* __restrict__ pos,
                            const int* __restrict__ rel, __bf16* __restrict__ wqkv,
                            __bf16* __restrict__ wo, float* __restrict__ bias,
                            __bf16* __restrict__ wqkvP, __bf16* __restrict__ woP) {
  const int idx = blockIdx.x * 256 + threadIdx.x;   // 0 .. 768*256-1
  const int row = idx >> 8, col = idx & 255;
  const float wv = (row < 256) ? Wq[idx] : Wkv[idx - 65536];
  wqkv[idx] = (__bf16)wv;
  {
    const int s = row >> 5, l31 = row & 31;
    const int ks = col >> 4, g2 = (col >> 3) & 1, e = col & 7;
    wqkvP[((size_t)((s * 16 + ks) * 64 + g2 * 32 + l31)) * 8 + e] = (__bf16)wv;
  }
  if (idx < 65536) {
    const float w = Wo[idx];
    wo[idx] = (__bf16)w;
    const int t = row >> 4, c16 = row & 15;
    const int kk = col >> 5, g4 = (col >> 3) & 3, e = col & 7;
    woP[((size_t)((t * 8 + kk) * 64 + g4 * 16 + c16)) * 8 + e] = (__bf16)w;
  }
  if (idx < 49 * 49) bias[idx] = pos[rel[idx * 2] * 13 + rel[idx * 2 + 1]];
}

// =====================================================================
// Merged kernel: x-stage -> QKV projection (packed weights) -> attention.
// v-pass A-fragments PREFETCHED at kernel entry (their latency hides under
// the x-staging; the __syncthreads vmcnt(0) drain lands them for free).
// MODE 1: writes attn + aoT_g (oproj finishes).  MODE 0: monolithic.
// =====================================================================
template <int MODE>
__global__ __launch_bounds__(256, 2) void attn_kernel(
    const float* __restrict__ x, const __bf16* __restrict__ wqkvP,
    const __bf16* __restrict__ wo, const float* __restrict__ bias_g,
    const float* __restrict__ bo_g, float* __restrict__ outg,
    float* __restrict__ attng, __bf16* __restrict__ aoT_g) {
  extern __shared__ char smem[];
  __bf16* xwT = (__bf16*)smem;
  __bf16* aoT = (__bf16*)smem;

  const int tid = threadIdx.x;
  const int bid = blockIdx.x;
  const int work = (bid & 7) * 512 + (bid >> 3);   // XCD swizzle
  const int b  = work >> 8;
  const int i1 = (work >> 4) & 15;
  const int i2 = work & 15;
  const int r0 = i1 * 7, c0 = i2 * 7;
  const int wave = tid >> 6, lane = tid & 63;
  const int l31 = lane & 31, g2 = lane >> 5;
  const int c16 = lane & 15, g4 = lane >> 4;
  char* slice = smem + wave * SLICE_B;

  // ---------- v-pass A prefetch (issue FIRST; lands during staging) ----------
  bf16x8 vA0[16], vA1[16];
  {
    const __bf16* A0p = wqkvP + (size_t)(16 + 2 * wave) * 8192 + lane * 8;
    const __bf16* A1p = A0p + 8192;
#pragma unroll
    for (int ks = 0; ks < 16; ++ks) {
      vA0[ks] = *(const bf16x8*)(A0p + ks * 512);
      vA1[ks] = *(const bf16x8*)(A1p + ks * 512);
    }
  }

  // ---------- phase 0: stage x window (wide loads, LDS transpose) ----------
  {
    bf16x8 z8;
#pragma unroll
    for (int j = 0; j < 8; ++j) z8[j] = (__bf16)0.f;
    for (int i = tid; i < 480; i += 256) {
      const int row = 49 + (i >> 5);
      const int col = (i & 31) * 8;
      *(bf16x8*)(xwT + row * XWT_PITCH + col) = z8;
    }
    f32x4a b4[7]; f32x2a b2[7]; float b1[7];
    int chv[7], rowv[7];
    const float* xb = x + (size_t)b * 256 * 12544;
#pragma unroll
    for (int k = 0; k < 7; ++k) {
      const int p = k * 256 + tid;
      const int ch = p / 7;
      const int row = p - ch * 7;
      chv[k] = ch; rowv[k] = row;
      const float* xr = xb + (size_t)ch * 12544 + (size_t)(r0 + row) * 112 + c0;
      b4[k] = *(const f32x4a*)xr;
      b2[k] = *(const f32x2a*)(xr + 4);
      b1[k] = xr[6];
    }
#pragma unroll
    for (int k = 0; k < 7; ++k) {
      __bf16* dst = xwT + (rowv[k] * 7) * XWT_PITCH + chv[k];
      dst[0 * XWT_PITCH] = (__bf16)b4[k][0];
      dst[1 * XWT_PITCH] = (__bf16)b4[k][1];
      dst[2 * XWT_PITCH] = (__bf16)b4[k][2];
      dst[3 * XWT_PITCH] = (__bf16)b4[k][3];
      dst[4 * XWT_PITCH] = (__bf16)b2[k][0];
      dst[5 * XWT_PITCH] = (__bf16)b2[k][1];
      dst[6 * XWT_PITCH] = (__bf16)b1[k];
    }
  }
  __syncthreads();

  // ---------- GEMM1 B-fragments (xw) -> registers ----------
  bf16x8 Bf0[16], Bf1[16];
  {
    const __bf16* Bp = xwT + l31 * XWT_PITCH + g2 * 8;
#pragma unroll
    for (int ks = 0; ks < 16; ++ks) {
      Bf0[ks] = *(const bf16x8*)(Bp + ks * 16);
      Bf1[ks] = *(const bf16x8*)(Bp + 32 * XWT_PITCH + ks * 16);
    }
  }
  __syncthreads();  // xwT dead; slices may now be written

  // ---------- GEMM1-v (A prefetched in vA0/vA1) ----------
  char* vsb = slice;
  {
    f32x16 a00 = zero16(), a01 = zero16(), a10 = zero16(), a11 = zero16();
    __builtin_amdgcn_s_setprio(1);
#pragma unroll
    for (int ks = 0; ks < 16; ++ks) {
      a00 = __builtin_amdgcn_mfma_f32_32x32x16_bf16(vA0[ks], Bf0[ks], a00, 0, 0, 0);
      a01 = __builtin_amdgcn_mfma_f32_32x32x16_bf16(vA0[ks], Bf1[ks], a01, 0, 0, 0);
      a10 = __builtin_amdgcn_mfma_f32_32x32x16_bf16(vA1[ks], Bf0[ks], a10, 0, 0, 0);
      a11 = __builtin_amdgcn_mfma_f32_32x32x16_bf16(vA1[ks], Bf1[ks], a11, 0, 0, 0);
    }
    __builtin_amdgcn_s_setprio(0);
#pragma unroll
    for (int rg = 0; rg < 16; ++rg) {
      const int dd = (rg & 3) + 8 * (rg >> 2) + 4 * g2;
      *(__bf16*)(vsb + dd * VS_ROW_B + l31 * 2)              = (__bf16)a00[rg];
      *(__bf16*)(vsb + dd * VS_ROW_B + 64 + l31 * 2)         = (__bf16)a01[rg];
      *(__bf16*)(vsb + (32 + dd) * VS_ROW_B + l31 * 2)       = (__bf16)a10[rg];
      *(__bf16*)(vsb + (32 + dd) * VS_ROW_B + 64 + l31 * 2)  = (__bf16)a11[rg];
    }
  }
  bf16x8 vf[2][2][2];
#pragma unroll
  for (int hh = 0; hh < 2; ++hh)
#pragma unroll
    for (int nt = 0; nt < 2; ++nt)
#pragma unroll
      for (int ks = 0; ks < 2; ++ks)
        vf[hh][nt][ks] = *(const bf16x8*)(vsb + (hh * 32 + nt * 16 + c16) * VS_ROW_B + ks * 64 + g4 * 16);
  asm volatile("s_waitcnt lgkmcnt(0)" ::: "memory");
  __builtin_amdgcn_sched_barrier(0x20);  // only VMEM_READ may cross

  // ---------- GEMM1-q (strips 2w,2w+1) and GEMM1-k (strips 8+2w,9+2w) ----------
  // only rows n_ < 49 stored (rows 49..63 would be discarded anyway)
#pragma unroll
  for (int qk = 0; qk < 2; ++qk) {
    const int koff = qk * 64;  // ELEMENT offset of k region within a row
    const __bf16* A0p = wqkvP + (size_t)(2 * wave + qk * 8) * 8192 + lane * 8;
    const __bf16* A1p = A0p + 8192;
    f32x16 a00 = zero16(), a01 = zero16(), a10 = zero16(), a11 = zero16();
    __builtin_amdgcn_s_setprio(1);
#pragma unroll
    for (int ks = 0; ks < 16; ++ks) {
      bf16x8 A0 = *(const bf16x8*)(A0p + ks * 512);
      bf16x8 A1 = *(const bf16x8*)(A1p + ks * 512);
      a00 = __builtin_amdgcn_mfma_f32_32x32x16_bf16(A0, Bf0[ks], a00, 0, 0, 0);
      a01 = __builtin_amdgcn_mfma_f32_32x32x16_bf16(A0, Bf1[ks], a01, 0, 0, 0);
      a10 = __builtin_amdgcn_mfma_f32_32x32x16_bf16(A1, Bf0[ks], a10, 0, 0, 0);
      a11 = __builtin_amdgcn_mfma_f32_32x32x16_bf16(A1, Bf1[ks], a11, 0, 0, 0);
    }
    __builtin_amdgcn_s_setprio(0);
#define STORE_QK(ACC, P_, NT)                                                  \
    {                                                                          \
      const int n_ = (NT) * 32 + l31;                                          \
      if (n_ < NPOS) {                                                         \
        _Pragma("unroll") for (int rb = 0; rb < 4; ++rb) {                     \
          const int ddb = koff + (P_) * 32 + rb * 8 + g2 * 4;                  \
          bf16x4 v4;                                                           \
          v4[0] = (__bf16)ACC[rb * 4 + 0]; v4[1] = (__bf16)ACC[rb * 4 + 1];    \
          v4[2] = (__bf16)ACC[rb * 4 + 2]; v4[3] = (__bf16)ACC[rb * 4 + 3];    \
          *(bf16x4*)(slice + n_ * QK_ROW_B + ddb * 2) = v4;                    \
        }                                                                      \
      }                                                                        \
    }
    STORE_QK(a00, 0, 0)
    STORE_QK(a01, 0, 1)
    STORE_QK(a10, 1, 0)
    STORE_QK(a11, 1, 1)
  }
  // fragment reads clamped to row 48 (rows 49..63 discarded/masked downstream)
  bf16x8 qf[2][4], kf[2][4];
#pragma unroll
  for (int t = 0; t < 4; ++t) {
    int rr = t * 16 + c16; rr = rr > 48 ? 48 : rr;
#pragma unroll
    for (int hh = 0; hh < 2; ++hh) {
      qf[hh][t] = *(const bf16x8*)(slice + rr * QK_ROW_B + hh * 64 + g4 * 16);
      kf[hh][t] = *(const bf16x8*)(slice + rr * QK_ROW_B + 128 + hh * 64 + g4 * 16);
    }
  }
  asm volatile("s_waitcnt lgkmcnt(0)" ::: "memory");
  __builtin_amdgcn_sched_barrier(0x20);

  // ---------- attention: both heads interleaved, barrier-free ----------
  f32x4 pacc[2][4][2];
  char* Pb0 = slice;
  char* Pb1 = slice + P1_OFF;
  {
    const f32x4 z4 = {0.f, 0.f, 0.f, 0.f};
    f32x4 dacc[2][4][4];
    __builtin_amdgcn_s_setprio(1);
#pragma unroll
    for (int hh = 0; hh < 2; ++hh)
#pragma unroll
      for (int mt = 0; mt < 4; ++mt)
#pragma unroll
        for (int nt = 0; nt < 4; ++nt)
          dacc[hh][mt][nt] = __builtin_amdgcn_mfma_f32_16x16x32_bf16(qf[hh][mt], kf[hh][nt], z4, 0, 0, 0);
    __builtin_amdgcn_s_setprio(0);

    const int h0 = wave * 2;
    // softmax WITHOUT max-subtraction (scores O(1); identical to ref math)
#pragma unroll
    for (int mt = 0; mt < 4; ++mt) {
#pragma unroll
      for (int r = 0; r < 4; ++r) {
        const int i = mt * 16 + g4 * 4 + r;
        float p0[4], p1[4], s0 = 0.f, s1 = 0.f;
#pragma unroll
        for (int nt = 0; nt < 4; ++nt) {
          const int j = nt * 16 + c16;
          float v0 = dacc[0][mt][nt][r] * SCALE_F;
          float v1 = dacc[1][mt][nt][r] * SCALE_F;
          if (j < NPOS) {
            if (i < NPOS) { const float bb = bias_g[i * 49 + j]; v0 += bb; v1 += bb; }
          } else {
            v0 = -1e30f; v1 = -1e30f;
          }
          p0[nt] = __expf(v0); s0 += p0[nt];
          p1[nt] = __expf(v1); s1 += p1[nt];
        }
        s0 += __shfl_xor(s0, 1); s1 += __shfl_xor(s1, 1);
        s0 += __shfl_xor(s0, 2); s1 += __shfl_xor(s1, 2);
        s0 += __shfl_xor(s0, 4); s1 += __shfl_xor(s1, 4);
        s0 += __shfl_xor(s0, 8); s1 += __shfl_xor(s1, 8);
        const float inv0 = 1.f / s0, inv1 = 1.f / s1;
        if (i < NPOS) {
          float* ap0 = attng + ((size_t)(work * NHEADS + h0) * 49 + i) * 49;
          float* ap1 = ap0 + 49 * 49;
#pragma unroll
          for (int nt = 0; nt < 4; ++nt) {
            const int j = nt * 16 + c16;
            const float q0 = p0[nt] * inv0, q1 = p1[nt] * inv1;
            if (j < NPOS) { ap0[j] = q0; ap1[j] = q1; }
            *(__bf16*)(Pb0 + i * 128 + 16 * ((j >> 3) ^ (i & 7)) + 2 * (j & 7)) = (__bf16)q0;
            *(__bf16*)(Pb1 + i * 128 + 16 * ((j >> 3) ^ (i & 7)) + 2 * (j & 7)) = (__bf16)q1;
          }
        }
      }
    }

    // PV (A-rows clamped to 48; those output rows are discarded)
    __builtin_amdgcn_s_setprio(1);
#pragma unroll
    for (int hh = 0; hh < 2; ++hh) {
      char* Pb = hh ? Pb1 : Pb0;
#pragma unroll
      for (int mt = 0; mt < 4; ++mt) {
        int i = mt * 16 + c16; i = i > 48 ? 48 : i;
        bf16x8 pa0 = *(const bf16x8*)(Pb + i * 128 + 16 * ((0 + g4) ^ (i & 7)));
        bf16x8 pa1 = *(const bf16x8*)(Pb + i * 128 + 16 * ((4 + g4) ^ (i & 7)));
#pragma unroll
        for (int nt = 0; nt < 2; ++nt) {
          f32x4 acc = {0.f, 0.f, 0.f, 0.f};
          acc = __builtin_amdgcn_mfma_f32_16x16x32_bf16(pa0, vf[hh][nt][0], acc, 0, 0, 0);
          acc = __builtin_amdgcn_mfma_f32_16x16x32_bf16(pa1, vf[hh][nt][1], acc, 0, 0, 0);
          pacc[hh][mt][nt] = acc;
        }
      }
    }
    __builtin_amdgcn_s_setprio(0);
  }

  if constexpr (MODE == 1) {
    // ---------- store attn_out (pre-Wo) -> aoT_g[win][49][256] bf16 ----------
    __bf16* ag = aoT_g + (size_t)work * 12544;
#pragma unroll
    for (int hh = 0; hh < 2; ++hh) {
      const int h = wave * 2 + hh;
#pragma unroll
      for (int mt = 0; mt < 4; ++mt)
#pragma unroll
        for (int e = 0; e < 4; ++e) {
          const int pos = mt * 16 + g4 * 4 + e;
          if (pos < NPOS) {
            ag[pos * 256 + h * 32 + c16]      = (__bf16)pacc[hh][mt][0][e];
            ag[pos * 256 + h * 32 + 16 + c16] = (__bf16)pacc[hh][mt][1][e];
          }
        }
    }
  } else {
    __syncthreads();
#pragma unroll
    for (int hh = 0; hh < 2; ++hh) {
      const int h = wave * 2 + hh;
#pragma unroll
      for (int mt = 0; mt < 4; ++mt)
#pragma unroll
        for (int nt = 0; nt < 2; ++nt)
#pragma unroll
          for (int e = 0; e < 4; ++e) {
            const int i = mt * 16 + g4 * 4 + e;
            const int cc = h * 32 + nt * 16 + c16;
            aoT[i * AOT_PITCH + cc] = (__bf16)pacc[hh][mt][nt][e];
          }
    }
    __syncthreads();
    {
      bf16x8 Cf0[16], Cf1[16];
      const __bf16* Bp = aoT + l31 * AOT_PITCH + g2 * 8;
#pragma unroll
      for (int ks = 0; ks < 16; ++ks) {
        Cf0[ks] = *(const bf16x8*)(Bp + ks * 16);
        Cf1[ks] = *(const bf16x8*)(Bp + 32 * AOT_PITCH + ks * 16);
      }
      const __bf16* Ap0 = wo + (size_t)(wave * 64 + l31) * 256 + g2 * 8;
      const __bf16* Ap1 = Ap0 + 32 * 256;
      f32x16 a00 = zero16(), a01 = zero16(), a10 = zero16(), a11 = zero16();
      __builtin_amdgcn_s_setprio(1);
#pragma unroll
      for (int ks = 0; ks < 16; ++ks) {
        bf16x8 A0 = *(const bf16x8*)(Ap0 + ks * 16);
        bf16x8 A1 = *(const bf16x8*)(Ap1 + ks * 16);
        a00 = __builtin_amdgcn_mfma_f32_32x32x16_bf16(A0, Cf0[ks], a00, 0, 0, 0);
        a01 = __builtin_amdgcn_mfma_f32_32x32x16_bf16(A0, Cf1[ks], a01, 0, 0, 0);
        a10 = __builtin_amdgcn_mfma_f32_32x32x16_bf16(A1, Cf0[ks], a10, 0, 0, 0);
        a11 = __builtin_amdgcn_mfma_f32_32x32x16_bf16(A1, Cf1[ks], a11, 0, 0, 0);
      }
      __builtin_amdgcn_s_setprio(0);
      float* og = outg + (size_t)b * 256 * 12544;
#define STORE_OUT(ACC, MT, NT)                                                    \
      {                                                                           \
        const int n_ = (NT) * 32 + l31;                                           \
        if (n_ < NPOS) {                                                          \
          const int pr_ = n_ / 7, pc_ = n_ - pr_ * 7;                             \
          float* orow = og + (size_t)(r0 + pr_) * 112 + (c0 + pc_);               \
          _Pragma("unroll") for (int rg = 0; rg < 16; ++rg) {                     \
            const int o2 = wave * 64 + (MT) * 32 + (rg & 3) + 8 * (rg >> 2) + 4 * g2; \
            orow[(size_t)o2 * 12544] = ACC[rg] + bo_g[o2];                        \
          }                                                                       \
        }                                                                         \
      }
      STORE_OUT(a00, 0, 0)
      STORE_OUT(a01, 0, 1)
      STORE_OUT(a10, 1, 0)
      STORE_OUT(a11, 1, 1)
    }
  }
}

// ---------------- oproj: out[b][oc][row][0..111] = Wo @ attn_out + bo ----------------
__global__ __launch_bounds__(256, 2) void oproj_kernel(
    const __bf16* __restrict__ aoT_g, const __bf16* __restrict__ woP,
    const float* __restrict__ bo_g, float* __restrict__ outg) {
  __shared__ __bf16 aoB[112 * 264];
  __shared__ float bo_s[256];
  const int tid = threadIdx.x;
  const int bid = blockIdx.x;
  const int work = (bid & 7) * 224 + (bid >> 3);
  const int pr = work % 7;
  const int g  = work / 7;
  const int i1 = g & 15, b = g >> 4;
  const int wave = tid >> 6, lane = tid & 63;
  const int c16 = lane & 15, g4 = lane >> 4;

  {
    const int rr = tid >> 5, coff = (tid & 31) * 8;
#pragma unroll
    for (int it = 0; it < 14; ++it) {
      const int gr = it * 8 + rr;
      const int i2 = gr / 7, pc = gr - i2 * 7;
      const size_t src = ((size_t)((b * 256 + i1 * 16 + i2) * 49 + pr * 7 + pc)) * 256 + coff;
      *(bf16x8*)(aoB + gr * 264 + coff) = *(const bf16x8*)(aoT_g + src);
    }
    bo_s[tid] = bo_g[tid];
  }
  __syncthreads();

  const int oc0 = wave * 64;
  const __bf16* Ap = woP + ((size_t)wave * 4 * 8) * 512 + lane * 8;
  f32x4 acc[4][7];
#pragma unroll
  for (int mt = 0; mt < 4; ++mt)
#pragma unroll
    for (int nt = 0; nt < 7; ++nt) acc[mt][nt] = f32x4{0.f, 0.f, 0.f, 0.f};
#pragma unroll
  for (int kk = 0; kk < 8; ++kk) {
    bf16x8 Af[4], Bf[7];
#pragma unroll
    for (int mt = 0; mt < 4; ++mt)
      Af[mt] = *(const bf16x8*)(Ap + (size_t)(mt * 8 + kk) * 512);
#pragma unroll
    for (int nt = 0; nt < 7; ++nt)
      Bf[nt] = *(const bf16x8*)(aoB + (nt * 16 + c16) * 264 + kk * 32 + g4 * 8);
    __builtin_amdgcn_s_setprio(1);
#pragma unroll
    for (int mt = 0; mt < 4; ++mt)
#pragma unroll
      for (int nt = 0; nt < 7; ++nt)
        acc[mt][nt] = __builtin_amdgcn_mfma_f32_16x16x32_bf16(Af[mt], Bf[nt], acc[mt][nt], 0, 0, 0);
    __builtin_amdgcn_s_setprio(0);
  }
  float* orow = outg + (size_t)b * 256 * 12544 + (size_t)(i1 * 7 + pr) * 112;
#pragma unroll
  for (int mt = 0; mt < 4; ++mt)
#pragma unroll
    for (int e = 0; e < 4; ++e) {
      const int oc = oc0 + mt * 16 + g4 * 4 + e;
      const float bb = bo_s[oc];
#pragma unroll
      for (int nt = 0; nt < 7; ++nt)
        orow[(size_t)oc * 12544 + nt * 16 + c16] = acc[mt][nt][e] + bb;
    }
}

extern "C" void kernel_launch(void* const* d_in, const int* in_sizes, int n_in,
                              void* d_out, int out_size, void* d_ws, size_t ws_size,
                              hipStream_t stream) {
  const float* x   = (const float*)d_in[0];
  const float* Wq  = (const float*)d_in[1];
  const float* Wkv = (const float*)d_in[2];
  const float* Wo  = (const float*)d_in[3];
  const float* bo  = (const float*)d_in[4];
  const float* pos = (const float*)d_in[5];
  const int*   rel = (const int*)d_in[6];

  float* outg  = (float*)d_out;
  float* attng = outg + (size_t)16 * 256 * 112 * 112;

  // ws layout: wqkv 393216 | wo 131072 | bias 9728 | wqkvP 393216 | woP 131072 | aoT
  __bf16* wqkv  = (__bf16*)d_ws;
  __bf16* wo    = (__bf16*)((char*)d_ws + 393216);
  float*  bias  = (float*)((char*)d_ws + 393216 + 131072);
  __bf16* wqkvP = (__bf16*)((char*)d_ws + 393216 + 131072 + 9728);
  __bf16* woP   = (__bf16*)((char*)d_ws + 393216 + 131072 + 9728 + 393216);
  size_t base = 393216 + 131072 + 9728 + 393216 + 131072;
  base = (base + 255) & ~(size_t)255;
  const size_t ao_bytes = (size_t)4096 * 12544 * 2;
  __bf16* aoT_g = (__bf16*)((char*)d_ws + base);
  (void)wqkv;

  hipFuncSetAttribute((const void*)attn_kernel<0>,
                      hipFuncAttributeMaxDynamicSharedMemorySize, LDS_BYTES);
  hipFuncSetAttribute((const void*)attn_kernel<1>,
                      hipFuncAttributeMaxDynamicSharedMemorySize, LDS_BYTES);

  prep_kernel<<<dim3(768), dim3(256), 0, stream>>>(Wq, Wkv, Wo, pos, rel, wqkv, wo, bias,
                                                   wqkvP, woP);
  if (ws_size >= base + ao_bytes) {
    attn_kernel<1><<<dim3(4096), dim3(256), LDS_BYTES, stream>>>(
        x, wqkvP, wo, bias, bo, outg, attng, aoT_g);
    oproj_kernel<<<dim3(1792), dim3(256), 0, stream>>>(aoT_g, woP, bo, outg);
  } else {
    attn_kernel<0><<<dim3(4096), dim3(256), LDS_BYTES, stream>>>(
        x, wqkvP, wo, bias, bo, outg, attng, nullptr);
  }
}

// Round 15
// 431.119 us; speedup vs baseline: 1.2520x; 1.2520x over previous
//
#include <hip/hip_runtime.h>
#include <hip/hip_bf16.h>

typedef __bf16 bf16x8 __attribute__((ext_vector_type(8)));
typedef __bf16 bf16x4 __attribute__((ext_vector_type(4)));
typedef float  f32x4  __attribute__((ext_vector_type(4)));
typedef float  f32x16 __attribute__((ext_vector_type(16)));
typedef float  f32x4a __attribute__((ext_vector_type(4))) __attribute__((aligned(4)));
typedef float  f32x2a __attribute__((ext_vector_type(2))) __attribute__((aligned(4)));

#define NPOS 49
#define NHEADS 8
#define SCALE_F 0.17677669529663687f

// ---- LDS: 4 per-wave slices of 13056 B = 52224 B total ----
// phase 0: smem[0..33792) = xwT [64 pos][264 ch] bf16 (overlays slices 0..2)
// phase A: slice+0 = vs [64 dd][68 pos] bf16 (8704 B)
// phase B: slice+0 = qk [49 pos][132 dd] bf16 (264 B rows; q=elem 0..63, k=64..127)
// phase C: Pb0 = slice+0, Pb1 = slice+6400 ([49 i][128 B] swizzled bf16 each)
// MODE 0 epilogue: smem[0..33792) = aoT [64][264] bf16
// NOTE (r10/r12/r14 lessons): 2 blocks/CU is the register-determined
// equilibrium (Bf=128 VGPR + 64 acc, unified file ~192/wave). Forcing 3
// waves/SIMD spills ~90 regs (2x regression); prefetching v-pass A across
// staging spills the prefetch (r14, +580MB scratch traffic). Do not touch
// launch bounds or add register-resident prefetches to this structure.
#define SLICE_B   13056
#define QK_ROW_B  264
#define VS_ROW_B  136
#define P1_OFF    6400
#define XWT_PITCH 264
#define AOT_PITCH 264
#define LDS_BYTES 52224

static __device__ __forceinline__ f32x16 zero16() {
  f32x16 z;
#pragma unroll
  for (int i = 0; i < 16; ++i) z[i] = 0.f;
  return z;
}

// prep: bf16 weight copies + MFMA-fragment-packed copies + bias table
__global__ void prep_kernel(const float* __restrict__ Wq, const float* __restrict__ Wkv,
                            const float* __restrict__ Wo, const float* __restrict__ pos,
                            const int* __restrict__ rel, __bf16* __restrict__ wqkv,
                            __bf16* __restrict__ wo, float* __restrict__ bias,
                            __bf16* __restrict__ wqkvP, __bf16* __restrict__ woP) {
  const int idx = blockIdx.x * 256 + threadIdx.x;   // 0 .. 768*256-1
  const int row = idx >> 8, col = idx & 255;
  const float wv = (row < 256) ? Wq[idx] : Wkv[idx - 65536];
  wqkv[idx] = (__bf16)wv;
  {
    const int s = row >> 5, l31 = row & 31;
    const int ks = col >> 4, g2 = (col >> 3) & 1, e = col & 7;
    wqkvP[((size_t)((s * 16 + ks) * 64 + g2 * 32 + l31)) * 8 + e] = (__bf16)wv;
  }
  if (idx < 65536) {
    const float w = Wo[idx];
    wo[idx] = (__bf16)w;
    const int t = row >> 4, c16 = row & 15;
    const int kk = col >> 5, g4 = (col >> 3) & 3, e = col & 7;
    woP[((size_t)((t * 8 + kk) * 64 + g4 * 16 + c16)) * 8 + e] = (__bf16)w;
  }
  if (idx < 49 * 49) bias[idx] = pos[rel[idx * 2] * 13 + rel[idx * 2 + 1]];
}

// =====================================================================
// Merged kernel: x-stage -> QKV projection (packed weights) -> attention.
// MODE 1: writes attn + aoT_g (oproj finishes).  MODE 0: monolithic.
// =====================================================================
template <int MODE>
__global__ __launch_bounds__(256, 2) void attn_kernel(
    const float* __restrict__ x, const __bf16* __restrict__ wqkvP,
    const __bf16* __restrict__ wo, const float* __restrict__ bias_g,
    const float* __restrict__ bo_g, float* __restrict__ outg,
    float* __restrict__ attng, __bf16* __restrict__ aoT_g) {
  extern __shared__ char smem[];
  __bf16* xwT = (__bf16*)smem;
  __bf16* aoT = (__bf16*)smem;

  const int tid = threadIdx.x;
  const int bid = blockIdx.x;
  const int work = (bid & 7) * 512 + (bid >> 3);   // XCD swizzle
  const int b  = work >> 8;
  const int i1 = (work >> 4) & 15;
  const int i2 = work & 15;
  const int r0 = i1 * 7, c0 = i2 * 7;
  const int wave = tid >> 6, lane = tid & 63;
  const int l31 = lane & 31, g2 = lane >> 5;
  const int c16 = lane & 15, g4 = lane >> 4;
  char* slice = smem + wave * SLICE_B;

  // ---------- phase 0: stage x window (wide loads, LDS transpose) ----------
  {
    bf16x8 z8;
#pragma unroll
    for (int j = 0; j < 8; ++j) z8[j] = (__bf16)0.f;
    for (int i = tid; i < 480; i += 256) {
      const int row = 49 + (i >> 5);
      const int col = (i & 31) * 8;
      *(bf16x8*)(xwT + row * XWT_PITCH + col) = z8;
    }
    f32x4a b4[7]; f32x2a b2[7]; float b1[7];
    int chv[7], rowv[7];
    const float* xb = x + (size_t)b * 256 * 12544;
#pragma unroll
    for (int k = 0; k < 7; ++k) {
      const int p = k * 256 + tid;
      const int ch = p / 7;
      const int row = p - ch * 7;
      chv[k] = ch; rowv[k] = row;
      const float* xr = xb + (size_t)ch * 12544 + (size_t)(r0 + row) * 112 + c0;
      b4[k] = *(const f32x4a*)xr;
      b2[k] = *(const f32x2a*)(xr + 4);
      b1[k] = xr[6];
    }
#pragma unroll
    for (int k = 0; k < 7; ++k) {
      __bf16* dst = xwT + (rowv[k] * 7) * XWT_PITCH + chv[k];
      dst[0 * XWT_PITCH] = (__bf16)b4[k][0];
      dst[1 * XWT_PITCH] = (__bf16)b4[k][1];
      dst[2 * XWT_PITCH] = (__bf16)b4[k][2];
      dst[3 * XWT_PITCH] = (__bf16)b4[k][3];
      dst[4 * XWT_PITCH] = (__bf16)b2[k][0];
      dst[5 * XWT_PITCH] = (__bf16)b2[k][1];
      dst[6 * XWT_PITCH] = (__bf16)b1[k];
    }
  }
  __syncthreads();

  // ---------- GEMM1 B-fragments (xw) -> registers ----------
  bf16x8 Bf0[16], Bf1[16];
  {
    const __bf16* Bp = xwT + l31 * XWT_PITCH + g2 * 8;
#pragma unroll
    for (int ks = 0; ks < 16; ++ks) {
      Bf0[ks] = *(const bf16x8*)(Bp + ks * 16);
      Bf1[ks] = *(const bf16x8*)(Bp + 32 * XWT_PITCH + ks * 16);
    }
  }
  __syncthreads();  // xwT dead; slices may now be written

  // ---------- GEMM1-v (packed strips 16+2w, 17+2w) ----------
  char* vsb = slice;
  {
    const __bf16* A0p = wqkvP + (size_t)(16 + 2 * wave) * 8192 + lane * 8;
    const __bf16* A1p = A0p + 8192;
    f32x16 a00 = zero16(), a01 = zero16(), a10 = zero16(), a11 = zero16();
    __builtin_amdgcn_s_setprio(1);
#pragma unroll
    for (int ks = 0; ks < 16; ++ks) {
      bf16x8 A0 = *(const bf16x8*)(A0p + ks * 512);
      bf16x8 A1 = *(const bf16x8*)(A1p + ks * 512);
      a00 = __builtin_amdgcn_mfma_f32_32x32x16_bf16(A0, Bf0[ks], a00, 0, 0, 0);
      a01 = __builtin_amdgcn_mfma_f32_32x32x16_bf16(A0, Bf1[ks], a01, 0, 0, 0);
      a10 = __builtin_amdgcn_mfma_f32_32x32x16_bf16(A1, Bf0[ks], a10, 0, 0, 0);
      a11 = __builtin_amdgcn_mfma_f32_32x32x16_bf16(A1, Bf1[ks], a11, 0, 0, 0);
    }
    __builtin_amdgcn_s_setprio(0);
#pragma unroll
    for (int rg = 0; rg < 16; ++rg) {
      const int dd = (rg & 3) + 8 * (rg >> 2) + 4 * g2;
      *(__bf16*)(vsb + dd * VS_ROW_B + l31 * 2)              = (__bf16)a00[rg];
      *(__bf16*)(vsb + dd * VS_ROW_B + 64 + l31 * 2)         = (__bf16)a01[rg];
      *(__bf16*)(vsb + (32 + dd) * VS_ROW_B + l31 * 2)       = (__bf16)a10[rg];
      *(__bf16*)(vsb + (32 + dd) * VS_ROW_B + 64 + l31 * 2)  = (__bf16)a11[rg];
    }
  }
  bf16x8 vf[2][2][2];
#pragma unroll
  for (int hh = 0; hh < 2; ++hh)
#pragma unroll
    for (int nt = 0; nt < 2; ++nt)
#pragma unroll
      for (int ks = 0; ks < 2; ++ks)
        vf[hh][nt][ks] = *(const bf16x8*)(vsb + (hh * 32 + nt * 16 + c16) * VS_ROW_B + ks * 64 + g4 * 16);
  asm volatile("s_waitcnt lgkmcnt(0)" ::: "memory");
  __builtin_amdgcn_sched_barrier(0x20);  // only VMEM_READ may cross

  // ---------- GEMM1-q (strips 2w,2w+1) and GEMM1-k (strips 8+2w,9+2w) ----------
  // only rows n_ < 49 stored (rows 49..63 would be discarded anyway)
#pragma unroll
  for (int qk = 0; qk < 2; ++qk) {
    const int koff = qk * 64;  // ELEMENT offset of k region within a row
    const __bf16* A0p = wqkvP + (size_t)(2 * wave + qk * 8) * 8192 + lane * 8;
    const __bf16* A1p = A0p + 8192;
    f32x16 a00 = zero16(), a01 = zero16(), a10 = zero16(), a11 = zero16();
    __builtin_amdgcn_s_setprio(1);
#pragma unroll
    for (int ks = 0; ks < 16; ++ks) {
      bf16x8 A0 = *(const bf16x8*)(A0p + ks * 512);
      bf16x8 A1 = *(const bf16x8*)(A1p + ks * 512);
      a00 = __builtin_amdgcn_mfma_f32_32x32x16_bf16(A0, Bf0[ks], a00, 0, 0, 0);
      a01 = __builtin_amdgcn_mfma_f32_32x32x16_bf16(A0, Bf1[ks], a01, 0, 0, 0);
      a10 = __builtin_amdgcn_mfma_f32_32x32x16_bf16(A1, Bf0[ks], a10, 0, 0, 0);
      a11 = __builtin_amdgcn_mfma_f32_32x32x16_bf16(A1, Bf1[ks], a11, 0, 0, 0);
    }
    __builtin_amdgcn_s_setprio(0);
#define STORE_QK(ACC, P_, NT)                                                  \
    {                                                                          \
      const int n_ = (NT) * 32 + l31;                                          \
      if (n_ < NPOS) {                                                         \
        _Pragma("unroll") for (int rb = 0; rb < 4; ++rb) {                     \
          const int ddb = koff + (P_) * 32 + rb * 8 + g2 * 4;                  \
          bf16x4 v4;                                                           \
          v4[0] = (__bf16)ACC[rb * 4 + 0]; v4[1] = (__bf16)ACC[rb * 4 + 1];    \
          v4[2] = (__bf16)ACC[rb * 4 + 2]; v4[3] = (__bf16)ACC[rb * 4 + 3];    \
          *(bf16x4*)(slice + n_ * QK_ROW_B + ddb * 2) = v4;                    \
        }                                                                      \
      }                                                                        \
    }
    STORE_QK(a00, 0, 0)
    STORE_QK(a01, 0, 1)
    STORE_QK(a10, 1, 0)
    STORE_QK(a11, 1, 1)
  }
  // fragment reads clamped to row 48 (rows 49..63 discarded/masked downstream)
  bf16x8 qf[2][4], kf[2][4];
#pragma unroll
  for (int t = 0; t < 4; ++t) {
    int rr = t * 16 + c16; rr = rr > 48 ? 48 : rr;
#pragma unroll
    for (int hh = 0; hh < 2; ++hh) {
      qf[hh][t] = *(const bf16x8*)(slice + rr * QK_ROW_B + hh * 64 + g4 * 16);
      kf[hh][t] = *(const bf16x8*)(slice + rr * QK_ROW_B + 128 + hh * 64 + g4 * 16);
    }
  }
  asm volatile("s_waitcnt lgkmcnt(0)" ::: "memory");
  __builtin_amdgcn_sched_barrier(0x20);

  // ---------- attention: both heads interleaved, barrier-free ----------
  f32x4 pacc[2][4][2];
  char* Pb0 = slice;
  char* Pb1 = slice + P1_OFF;
  {
    const f32x4 z4 = {0.f, 0.f, 0.f, 0.f};
    f32x4 dacc[2][4][4];
    __builtin_amdgcn_s_setprio(1);
#pragma unroll
    for (int hh = 0; hh < 2; ++hh)
#pragma unroll
      for (int mt = 0; mt < 4; ++mt)
#pragma unroll
        for (int nt = 0; nt < 4; ++nt)
          dacc[hh][mt][nt] = __builtin_amdgcn_mfma_f32_16x16x32_bf16(qf[hh][mt], kf[hh][nt], z4, 0, 0, 0);
    __builtin_amdgcn_s_setprio(0);

    const int h0 = wave * 2;
    // softmax WITHOUT max-subtraction (scores O(1); identical to ref math)
#pragma unroll
    for (int mt = 0; mt < 4; ++mt) {
#pragma unroll
      for (int r = 0; r < 4; ++r) {
        const int i = mt * 16 + g4 * 4 + r;
        float p0[4], p1[4], s0 = 0.f, s1 = 0.f;
#pragma unroll
        for (int nt = 0; nt < 4; ++nt) {
          const int j = nt * 16 + c16;
          float v0 = dacc[0][mt][nt][r] * SCALE_F;
          float v1 = dacc[1][mt][nt][r] * SCALE_F;
          if (j < NPOS) {
            if (i < NPOS) { const float bb = bias_g[i * 49 + j]; v0 += bb; v1 += bb; }
          } else {
            v0 = -1e30f; v1 = -1e30f;
          }
          p0[nt] = __expf(v0); s0 += p0[nt];
          p1[nt] = __expf(v1); s1 += p1[nt];
        }
        s0 += __shfl_xor(s0, 1); s1 += __shfl_xor(s1, 1);
        s0 += __shfl_xor(s0, 2); s1 += __shfl_xor(s1, 2);
        s0 += __shfl_xor(s0, 4); s1 += __shfl_xor(s1, 4);
        s0 += __shfl_xor(s0, 8); s1 += __shfl_xor(s1, 8);
        const float inv0 = 1.f / s0, inv1 = 1.f / s1;
        if (i < NPOS) {
          float* ap0 = attng + ((size_t)(work * NHEADS + h0) * 49 + i) * 49;
          float* ap1 = ap0 + 49 * 49;
#pragma unroll
          for (int nt = 0; nt < 4; ++nt) {
            const int j = nt * 16 + c16;
            const float q0 = p0[nt] * inv0, q1 = p1[nt] * inv1;
            if (j < NPOS) { ap0[j] = q0; ap1[j] = q1; }
            *(__bf16*)(Pb0 + i * 128 + 16 * ((j >> 3) ^ (i & 7)) + 2 * (j & 7)) = (__bf16)q0;
            *(__bf16*)(Pb1 + i * 128 + 16 * ((j >> 3) ^ (i & 7)) + 2 * (j & 7)) = (__bf16)q1;
          }
        }
      }
    }

    // PV (A-rows clamped to 48; those output rows are discarded)
    __builtin_amdgcn_s_setprio(1);
#pragma unroll
    for (int hh = 0; hh < 2; ++hh) {
      char* Pb = hh ? Pb1 : Pb0;
#pragma unroll
      for (int mt = 0; mt < 4; ++mt) {
        int i = mt * 16 + c16; i = i > 48 ? 48 : i;
        bf16x8 pa0 = *(const bf16x8*)(Pb + i * 128 + 16 * ((0 + g4) ^ (i & 7)));
        bf16x8 pa1 = *(const bf16x8*)(Pb + i * 128 + 16 * ((4 + g4) ^ (i & 7)));
#pragma unroll
        for (int nt = 0; nt < 2; ++nt) {
          f32x4 acc = {0.f, 0.f, 0.f, 0.f};
          acc = __builtin_amdgcn_mfma_f32_16x16x32_bf16(pa0, vf[hh][nt][0], acc, 0, 0, 0);
          acc = __builtin_amdgcn_mfma_f32_16x16x32_bf16(pa1, vf[hh][nt][1], acc, 0, 0, 0);
          pacc[hh][mt][nt] = acc;
        }
      }
    }
    __builtin_amdgcn_s_setprio(0);
  }

  if constexpr (MODE == 1) {
    // ---------- store attn_out (pre-Wo) -> aoT_g[win][49][256] bf16 ----------
    __bf16* ag = aoT_g + (size_t)work * 12544;
#pragma unroll
    for (int hh = 0; hh < 2; ++hh) {
      const int h = wave * 2 + hh;
#pragma unroll
      for (int mt = 0; mt < 4; ++mt)
#pragma unroll
        for (int e = 0; e < 4; ++e) {
          const int pos = mt * 16 + g4 * 4 + e;
          if (pos < NPOS) {
            ag[pos * 256 + h * 32 + c16]      = (__bf16)pacc[hh][mt][0][e];
            ag[pos * 256 + h * 32 + 16 + c16] = (__bf16)pacc[hh][mt][1][e];
          }
        }
    }
  } else {
    __syncthreads();
#pragma unroll
    for (int hh = 0; hh < 2; ++hh) {
      const int h = wave * 2 + hh;
#pragma unroll
      for (int mt = 0; mt < 4; ++mt)
#pragma unroll
        for (int nt = 0; nt < 2; ++nt)
#pragma unroll
          for (int e = 0; e < 4; ++e) {
            const int i = mt * 16 + g4 * 4 + e;
            const int cc = h * 32 + nt * 16 + c16;
            aoT[i * AOT_PITCH + cc] = (__bf16)pacc[hh][mt][nt][e];
          }
    }
    __syncthreads();
    {
      bf16x8 Cf0[16], Cf1[16];
      const __bf16* Bp = aoT + l31 * AOT_PITCH + g2 * 8;
#pragma unroll
      for (int ks = 0; ks < 16; ++ks) {
        Cf0[ks] = *(const bf16x8*)(Bp + ks * 16);
        Cf1[ks] = *(const bf16x8*)(Bp + 32 * AOT_PITCH + ks * 16);
      }
      const __bf16* Ap0 = wo + (size_t)(wave * 64 + l31) * 256 + g2 * 8;
      const __bf16* Ap1 = Ap0 + 32 * 256;
      f32x16 a00 = zero16(), a01 = zero16(), a10 = zero16(), a11 = zero16();
      __builtin_amdgcn_s_setprio(1);
#pragma unroll
      for (int ks = 0; ks < 16; ++ks) {
        bf16x8 A0 = *(const bf16x8*)(Ap0 + ks * 16);
        bf16x8 A1 = *(const bf16x8*)(Ap1 + ks * 16);
        a00 = __builtin_amdgcn_mfma_f32_32x32x16_bf16(A0, Cf0[ks], a00, 0, 0, 0);
        a01 = __builtin_amdgcn_mfma_f32_32x32x16_bf16(A0, Cf1[ks], a01, 0, 0, 0);
        a10 = __builtin_amdgcn_mfma_f32_32x32x16_bf16(A1, Cf0[ks], a10, 0, 0, 0);
        a11 = __builtin_amdgcn_mfma_f32_32x32x16_bf16(A1, Cf1[ks], a11, 0, 0, 0);
      }
      __builtin_amdgcn_s_setprio(0);
      float* og = outg + (size_t)b * 256 * 12544;
#define STORE_OUT(ACC, MT, NT)                                                    \
      {                                                                           \
        const int n_ = (NT) * 32 + l31;                                           \
        if (n_ < NPOS) {                                                          \
          const int pr_ = n_ / 7, pc_ = n_ - pr_ * 7;                             \
          float* orow = og + (size_t)(r0 + pr_) * 112 + (c0 + pc_);               \
          _Pragma("unroll") for (int rg = 0; rg < 16; ++rg) {                     \
            const int o2 = wave * 64 + (MT) * 32 + (rg & 3) + 8 * (rg >> 2) + 4 * g2; \
            orow[(size_t)o2 * 12544] = ACC[rg] + bo_g[o2];                        \
          }                                                                       \
        }                                                                         \
      }
      STORE_OUT(a00, 0, 0)
      STORE_OUT(a01, 0, 1)
      STORE_OUT(a10, 1, 0)
      STORE_OUT(a11, 1, 1)
    }
  }
}

// ---------------- oproj: out[b][oc][row][0..111] = Wo @ attn_out + bo ----------------
__global__ __launch_bounds__(256, 2) void oproj_kernel(
    const __bf16* __restrict__ aoT_g, const __bf16* __restrict__ woP,
    const float* __restrict__ bo_g, float* __restrict__ outg) {
  __shared__ __bf16 aoB[112 * 264];
  __shared__ float bo_s[256];
  const int tid = threadIdx.x;
  const int bid = blockIdx.x;
  const int work = (bid & 7) * 224 + (bid >> 3);
  const int pr = work % 7;
  const int g  = work / 7;
  const int i1 = g & 15, b = g >> 4;
  const int wave = tid >> 6, lane = tid & 63;
  const int c16 = lane & 15, g4 = lane >> 4;

  {
    const int rr = tid >> 5, coff = (tid & 31) * 8;
#pragma unroll
    for (int it = 0; it < 14; ++it) {
      const int gr = it * 8 + rr;
      const int i2 = gr / 7, pc = gr - i2 * 7;
      const size_t src = ((size_t)((b * 256 + i1 * 16 + i2) * 49 + pr * 7 + pc)) * 256 + coff;
      *(bf16x8*)(aoB + gr * 264 + coff) = *(const bf16x8*)(aoT_g + src);
    }
    bo_s[tid] = bo_g[tid];
  }
  __syncthreads();

  const int oc0 = wave * 64;
  const __bf16* Ap = woP + ((size_t)wave * 4 * 8) * 512 + lane * 8;
  f32x4 acc[4][7];
#pragma unroll
  for (int mt = 0; mt < 4; ++mt)
#pragma unroll
    for (int nt = 0; nt < 7; ++nt) acc[mt][nt] = f32x4{0.f, 0.f, 0.f, 0.f};
#pragma unroll
  for (int kk = 0; kk < 8; ++kk) {
    bf16x8 Af[4], Bf[7];
#pragma unroll
    for (int mt = 0; mt < 4; ++mt)
      Af[mt] = *(const bf16x8*)(Ap + (size_t)(mt * 8 + kk) * 512);
#pragma unroll
    for (int nt = 0; nt < 7; ++nt)
      Bf[nt] = *(const bf16x8*)(aoB + (nt * 16 + c16) * 264 + kk * 32 + g4 * 8);
    __builtin_amdgcn_s_setprio(1);
#pragma unroll
    for (int mt = 0; mt < 4; ++mt)
#pragma unroll
      for (int nt = 0; nt < 7; ++nt)
        acc[mt][nt] = __builtin_amdgcn_mfma_f32_16x16x32_bf16(Af[mt], Bf[nt], acc[mt][nt], 0, 0, 0);
    __builtin_amdgcn_s_setprio(0);
  }
  float* orow = outg + (size_t)b * 256 * 12544 + (size_t)(i1 * 7 + pr) * 112;
#pragma unroll
  for (int mt = 0; mt < 4; ++mt)
#pragma unroll
    for (int e = 0; e < 4; ++e) {
      const int oc = oc0 + mt * 16 + g4 * 4 + e;
      const float bb = bo_s[oc];
#pragma unroll
      for (int nt = 0; nt < 7; ++nt)
        orow[(size_t)oc * 12544 + nt * 16 + c16] = acc[mt][nt][e] + bb;
    }
}

extern "C" void kernel_launch(void* const* d_in, const int* in_sizes, int n_in,
                              void* d_out, int out_size, void* d_ws, size_t ws_size,
                              hipStream_t stream) {
  const float* x   = (const float*)d_in[0];
  const float* Wq  = (const float*)d_in[1];
  const float* Wkv = (const float*)d_in[2];
  const float* Wo  = (const float*)d_in[3];
  const float* bo  = (const float*)d_in[4];
  const float* pos = (const float*)d_in[5];
  const int*   rel = (const int*)d_in[6];

  float* outg  = (float*)d_out;
  float* attng = outg + (size_t)16 * 256 * 112 * 112;

  // ws layout: wqkv 393216 | wo 131072 | bias 9728 | wqkvP 393216 | woP 131072 | aoT
  __bf16* wqkv  = (__bf16*)d_ws;
  __bf16* wo    = (__bf16*)((char*)d_ws + 393216);
  float*  bias  = (float*)((char*)d_ws + 393216 + 131072);
  __bf16* wqkvP = (__bf16*)((char*)d_ws + 393216 + 131072 + 9728);
  __bf16* woP   = (__bf16*)((char*)d_ws + 393216 + 131072 + 9728 + 393216);
  size_t base = 393216 + 131072 + 9728 + 393216 + 131072;
  base = (base + 255) & ~(size_t)255;
  const size_t ao_bytes = (size_t)4096 * 12544 * 2;
  __bf16* aoT_g = (__bf16*)((char*)d_ws + base);
  (void)wqkv;

  hipFuncSetAttribute((const void*)attn_kernel<0>,
                      hipFuncAttributeMaxDynamicSharedMemorySize, LDS_BYTES);
  hipFuncSetAttribute((const void*)attn_kernel<1>,
                      hipFuncAttributeMaxDynamicSharedMemorySize, LDS_BYTES);

  prep_kernel<<<dim3(768), dim3(256), 0, stream>>>(Wq, Wkv, Wo, pos, rel, wqkv, wo, bias,
                                                   wqkvP, woP);
  if (ws_size >= base + ao_bytes) {
    attn_kernel<1><<<dim3(4096), dim3(256), LDS_BYTES, stream>>>(
        x, wqkvP, wo, bias, bo, outg, attng, aoT_g);
    oproj_kernel<<<dim3(1792), dim3(256), 0, stream>>>(aoT_g, woP, bo, outg);
  } else {
    attn_kernel<0><<<dim3(4096), dim3(256), LDS_BYTES, stream>>>(
        x, wqkvP, wo, bias, bo, outg, attng, nullptr);
  }
}